// Round 18
// baseline (102.434 us; speedup 1.0000x reference)
//
#include <hip/hip_runtime.h>
#include <hip/hip_bf16.h>
#include <math.h>

typedef __bf16 bf16x8 __attribute__((ext_vector_type(8)));
typedef __bf16 bf16x4 __attribute__((ext_vector_type(4)));
typedef float  f32x4  __attribute__((ext_vector_type(4)));

#define MFMA16(a, b, c) __builtin_amdgcn_mfma_f32_16x16x32_bf16((a), (b), (c), 0, 0, 0)

__device__ __forceinline__ void gload16(const void* g, void* lds) {
    __builtin_amdgcn_global_load_lds(
        (const __attribute__((address_space(1))) uint32_t*)g,
        (__attribute__((address_space(3))) uint32_t*)lds, 16, 0, 0);
}

// ---------------------------------------------------------------------------
// prep3: transpose-cast weights only (x-cast now fused into gemm_qkv).
// idx 0..1023: n0=(idx&15)*64, k0=((idx>>4)&15)*64, z=idx>>8.
__global__ __launch_bounds__(256)
void prep3_kernel(const float* __restrict__ Wq, const float* __restrict__ Wk,
                  const float* __restrict__ Wv, const float* __restrict__ Wproj,
                  __bf16* __restrict__ wqkvt, __bf16* __restrict__ wprojt) {
    __shared__ __bf16 Ts[64 * 72];
    const int idx = blockIdx.x;
    const int tid = threadIdx.x;
    const int z = idx >> 8;
    const float* W = (z == 0) ? Wq : (z == 1) ? Wk : (z == 2) ? Wv : Wproj;
    __bf16* dst = (z == 3) ? wprojt : wqkvt;
    const int N = (z == 1 || z == 2) ? 512 : 1024;
    const int nt_off = (z == 1) ? 1024 : (z == 2) ? 1536 : 0;
    const int n0 = (idx & 15) * 64, k0 = ((idx >> 4) & 15) * 64;
    if (n0 >= N) return;
    {
        int r = tid >> 2;              // k-row 0..63
        int c0 = (tid & 3) * 16;       // n-col start
        const float4* s4 = reinterpret_cast<const float4*>(
            W + (size_t)(k0 + r) * N + n0 + c0);
        float val[16];
        #pragma unroll
        for (int q = 0; q < 4; ++q) {
            float4 v = s4[q];
            val[q * 4 + 0] = v.x; val[q * 4 + 1] = v.y;
            val[q * 4 + 2] = v.z; val[q * 4 + 3] = v.w;
        }
        #pragma unroll
        for (int j = 0; j < 16; ++j) Ts[(c0 + j) * 72 + r] = (__bf16)val[j];
    }
    __syncthreads();
    {
        int n = tid >> 2, kg = (tid & 3) * 16;
        __bf16* out = dst + (size_t)(nt_off + n0 + n) * 1024 + k0 + kg;
        bf16x8 t0 = *reinterpret_cast<const bf16x8*>(&Ts[n * 72 + kg]);
        bf16x8 t1 = *reinterpret_cast<const bf16x8*>(&Ts[n * 72 + kg + 8]);
        *reinterpret_cast<bf16x8*>(out) = t0;
        *reinterpret_cast<bf16x8*>(out + 8) = t1;
    }
}

// ---------------------------------------------------------------------------
// gemm_qkv: 128x128 tile, BK=64, 4 waves. A read DIRECTLY as f32 (x) with
// in-staging conversion (reg-staged float4 x2 -> bf16x8 -> swizzled ds_write,
// write-side XOR == read-side involution). B via gload_lds from bf16 Bt.
// Removes the separate x-cast pass (prep 9 -> ~5 us).
__global__ __launch_bounds__(256)
void gemm_qkv(const float* __restrict__ A32, const __bf16* __restrict__ Bt,
              __bf16* __restrict__ C, int M, int N, int K) {
    __shared__ __align__(16) __bf16 As[128 * 64];
    __shared__ __align__(16) __bf16 Bs[128 * 64];
    const int tid = threadIdx.x;
    const int lane = tid & 63, w = tid >> 6;
    const int wr = w >> 1, wc = w & 1;
    const int nwg = gridDim.x * gridDim.y;
    const int id = blockIdx.y * gridDim.x + blockIdx.x;
    const int nid = (id & 7) * (nwg >> 3) + (id >> 3);
    const int bxs = nid % gridDim.x, bys = nid / gridDim.x;
    const int bm = bys * 128, bn = bxs * 128;
    const int lhi = lane >> 4, llo = lane & 15;
    const int gsrc = (lane & 7) ^ ((lane >> 3) & 7);

    f32x4 acc[4][4] = {};

    for (int k0 = 0; k0 < K; k0 += 64) {
        __syncthreads();
        const __bf16* Bb = Bt + (size_t)bn * K + k0;
        #pragma unroll
        for (int rr = 0; rr < 4; ++rr) {
            int c = rr * 4 + w;
            int r = c * 8 + (lane >> 3);
            gload16(Bb + (size_t)r * K + gsrc * 8, (char*)Bs + c * 1024);
            // A: f32 source, convert during staging
            const float* ap = A32 + (size_t)(bm + r) * K + k0 + (lane & 7) * 8;
            float4 a0 = *(const float4*)ap;
            float4 a1 = *(const float4*)(ap + 4);
            bf16x8 o = { (__bf16)a0.x, (__bf16)a0.y, (__bf16)a0.z, (__bf16)a0.w,
                         (__bf16)a1.x, (__bf16)a1.y, (__bf16)a1.z, (__bf16)a1.w };
            *(bf16x8*)((char*)As + r * 128 + (((lane & 7) ^ (r & 7)) << 4)) = o;
        }
        __syncthreads();

        #pragma unroll
        for (int ks = 0; ks < 2; ++ks) {
            bf16x8 af[4], bfr[4];
            int g = ks * 4 + lhi;
            #pragma unroll
            for (int i = 0; i < 4; ++i) {
                int ra = wr * 64 + i * 16 + llo;
                af[i] = *reinterpret_cast<const bf16x8*>(
                    (const char*)As + ra * 128 + ((g ^ (ra & 7)) << 4));
                int rb = wc * 64 + i * 16 + llo;
                bfr[i] = *reinterpret_cast<const bf16x8*>(
                    (const char*)Bs + rb * 128 + ((g ^ (rb & 7)) << 4));
            }
            #pragma unroll
            for (int i = 0; i < 4; ++i)
                #pragma unroll
                for (int j = 0; j < 4; ++j)
                    acc[i][j] = MFMA16(af[i], bfr[j], acc[i][j]);
        }
    }

    #pragma unroll
    for (int i = 0; i < 4; ++i) {
        #pragma unroll
        for (int j = 0; j < 4; ++j) {
            int col = bn + wc * 64 + j * 16 + llo;
            #pragma unroll
            for (int r = 0; r < 4; ++r) {
                int row = bm + wr * 64 + i * 16 + lhi * 4 + r;
                C[(size_t)row * N + col] = (__bf16)acc[i][j][r];
            }
        }
    }
}

// ---------------------------------------------------------------------------
// gemm64: 64(M) x 128(N) tile, BK=64, 4 waves each 64x32 (proj: 2 blocks/CU).
template <typename OutT>
__global__ __launch_bounds__(256)
void gemm64_bf16(const __bf16* __restrict__ A, const __bf16* __restrict__ Bt,
                 OutT* __restrict__ C, int M, int N, int K) {
    __shared__ __align__(16) __bf16 As[64 * 64];     //  8 KB
    __shared__ __align__(16) __bf16 Bs[128 * 64];    // 16 KB
    const int tid = threadIdx.x;
    const int lane = tid & 63, w = tid >> 6;
    const int nwg = gridDim.x * gridDim.y;
    const int id = blockIdx.y * gridDim.x + blockIdx.x;
    const int nid = (id & 7) * (nwg >> 3) + (id >> 3);
    const int bxs = nid % gridDim.x, bys = nid / gridDim.x;
    const int bm = bys * 64, bn = bxs * 128;
    const int lhi = lane >> 4, llo = lane & 15;
    const int gsrc = (lane & 7) ^ ((lane >> 3) & 7);

    f32x4 acc[4][2] = {};

    for (int k0 = 0; k0 < K; k0 += 64) {
        __syncthreads();
        const __bf16* Ab = A + (size_t)bm * K + k0;
        const __bf16* Bb = Bt + (size_t)bn * K + k0;
        #pragma unroll
        for (int rr = 0; rr < 2; ++rr) {
            int c = rr * 4 + w;            // 0..7
            int r = c * 8 + (lane >> 3);   // 0..63
            gload16(Ab + (size_t)r * K + gsrc * 8, (char*)As + c * 1024);
        }
        #pragma unroll
        for (int rr = 0; rr < 4; ++rr) {
            int c = rr * 4 + w;            // 0..15
            int r = c * 8 + (lane >> 3);   // 0..127
            gload16(Bb + (size_t)r * K + gsrc * 8, (char*)Bs + c * 1024);
        }
        __syncthreads();

        #pragma unroll
        for (int ks = 0; ks < 2; ++ks) {
            int g = ks * 4 + lhi;
            bf16x8 af[4], bfr[2];
            #pragma unroll
            for (int i = 0; i < 4; ++i) {
                int ra = i * 16 + llo;
                af[i] = *reinterpret_cast<const bf16x8*>(
                    (const char*)As + ra * 128 + ((g ^ (ra & 7)) << 4));
            }
            #pragma unroll
            for (int j = 0; j < 2; ++j) {
                int rb = w * 32 + j * 16 + llo;
                bfr[j] = *reinterpret_cast<const bf16x8*>(
                    (const char*)Bs + rb * 128 + ((g ^ (rb & 7)) << 4));
            }
            #pragma unroll
            for (int i = 0; i < 4; ++i)
                #pragma unroll
                for (int j = 0; j < 2; ++j)
                    acc[i][j] = MFMA16(af[i], bfr[j], acc[i][j]);
        }
    }

    #pragma unroll
    for (int i = 0; i < 4; ++i) {
        #pragma unroll
        for (int j = 0; j < 2; ++j) {
            int col = bn + w * 32 + j * 16 + llo;
            #pragma unroll
            for (int r = 0; r < 4; ++r) {
                int row = bm + i * 16 + lhi * 4 + r;
                C[(size_t)row * N + col] = (OutT)acc[i][j][r];
            }
        }
    }
}

// ---------------------------------------------------------------------------
// post2: vectorized RoPE+RMS (blocks 0..3071, 8 elems/lane) ;
// v-gate + transpose (blocks 3072..3583) with inline gate.
// Q heads scaled by 0.125*log2(e) (exp2-domain softmax).
__global__ __launch_bounds__(256)
void post2_kernel(__bf16* __restrict__ qkv, const float* __restrict__ x,
                  const float* __restrict__ ve, const float* __restrict__ Wg,
                  const float* __restrict__ cosb, const float* __restrict__ sinb,
                  __bf16* __restrict__ vT) {
    const int id = blockIdx.x;
    const int tid = threadIdx.x;
    if (id < 3072) {
        // RoPE+RMS: u = id>>7 (head unit), 32 rows/block, 8 lanes/row
        const int u = id >> 7;                      // 0..23
        const int row = (id & 127) * 32 + (tid >> 3);
        const int j = tid & 7;                      // 8 elems each
        const int t = row & 2047;
        const int off = (u < 16) ? u * 64 : 1024 + (u - 16) * 64;
        __bf16* p = qkv + (size_t)row * 2048 + off + j * 8;
        bf16x8 v8 = *(const bf16x8*)p;
        float v[8], pr[8];
        #pragma unroll
        for (int e = 0; e < 8; ++e) v[e] = (float)v8[e];
        #pragma unroll
        for (int e = 0; e < 8; ++e) pr[e] = __shfl_xor(v[e], 4, 64);  // d^32
        const float* cp = cosb + t * 32 + (j & 3) * 8;
        const float* sp = sinb + t * 32 + (j & 3) * 8;
        float4 c0 = *(const float4*)cp, c1 = *(const float4*)(cp + 4);
        float4 s0 = *(const float4*)sp, s1 = *(const float4*)(sp + 4);
        float cs[8] = {c0.x, c0.y, c0.z, c0.w, c1.x, c1.y, c1.z, c1.w};
        float sn[8] = {s0.x, s0.y, s0.z, s0.w, s1.x, s1.y, s1.z, s1.w};
        float r[8];
        if (j < 4) {
            #pragma unroll
            for (int e = 0; e < 8; ++e) r[e] = v[e] * cs[e] + pr[e] * sn[e];
        } else {
            #pragma unroll
            for (int e = 0; e < 8; ++e) r[e] = v[e] * cs[e] - pr[e] * sn[e];
        }
        float s = 0.f;
        #pragma unroll
        for (int e = 0; e < 8; ++e) s = fmaf(r[e], r[e], s);
        s += __shfl_xor(s, 1, 64);
        s += __shfl_xor(s, 2, 64);
        s += __shfl_xor(s, 4, 64);
        float scale = rsqrtf(s * (1.0f / 64.0f) + 1.1920929e-07f);
        if (u < 16) scale *= 0.18033688011116012f;  // 0.125 * log2(e)
        bf16x8 o;
        #pragma unroll
        for (int e = 0; e < 8; ++e) o[e] = (__bf16)(r[e] * scale);
        *(bf16x8*)p = o;
    } else {
        __shared__ __bf16 Ts[64 * 72];
        const int rem = id - 3072;
        const int ch = rem & 63;    // 64-row chunk
        const int h = rem >> 6;     // 0..7
        {
            int r = tid >> 2, c0 = (tid & 3) * 16;
            int grow = ch * 64 + r;
            // inline gate: 4 lanes/row each sum 8 terms, combine via shfl
            float gz = 0.f;
            {
                const float* xr = x + (size_t)grow * 1024 + (tid & 3) * 8;
                #pragma unroll
                for (int i = 0; i < 8; ++i)
                    gz = fmaf(xr[i], Wg[((tid & 3) * 8 + i) * 8 + h], gz);
                gz += __shfl_xor(gz, 1, 64);
                gz += __shfl_xor(gz, 2, 64);
            }
            float g = 2.0f / (1.0f + expf(-gz));
            const __bf16* vp = qkv + (size_t)grow * 2048 + 1536 + h * 64 + c0;
            const float* vep = ve + (size_t)grow * 512 + h * 64 + c0;
            bf16x8 v0 = *reinterpret_cast<const bf16x8*>(vp);
            bf16x8 v1 = *reinterpret_cast<const bf16x8*>(vp + 8);
            #pragma unroll
            for (int j = 0; j < 8; ++j) {
                Ts[(c0 + j) * 72 + r]     = (__bf16)((float)v0[j] + g * vep[j]);
                Ts[(c0 + 8 + j) * 72 + r] = (__bf16)((float)v1[j] + g * vep[8 + j]);
            }
        }
        __syncthreads();
        {
            int d = tid >> 2, t0l = (tid & 3) * 16;
            int b = ch >> 5, tloc = (ch & 31) * 64;
            __bf16* out = vT + ((size_t)((b * 8 + h) * 64 + d)) * 2048 + tloc + t0l;
            bf16x8 t0 = *reinterpret_cast<const bf16x8*>(&Ts[d * 72 + t0l]);
            bf16x8 t1 = *reinterpret_cast<const bf16x8*>(&Ts[d * 72 + t0l + 8]);
            *reinterpret_cast<bf16x8*>(out) = t0;
            *reinterpret_cast<bf16x8*>(out + 8) = t1;
        }
    }
}

// ---------------------------------------------------------------------------
// MFMA flash attention v9 (proven 41us): QBLK=64 (4 waves x 16 q-rows),
// KVBLK=64, grid 1024. Single-buffered gload_lds staging: STAGE -> barrier ->
// compute -> barrier. LDS = 24576 B. XCD-locality (kvh in low 3 bits), LPT,
// no-bias exp2 softmax (scale-invariant, |s|<=~11.8), tree-sum denominator.
__global__ __launch_bounds__(256, 6)
void attn_mfma(const __bf16* __restrict__ qkv, const __bf16* __restrict__ vT,
               __bf16* __restrict__ y, const int* __restrict__ winp) {
    __shared__ __align__(16) __bf16 Ks[64 * 64];       // 8 KB
    __shared__ __align__(16) __bf16 VTs[64 * 64];      // 8 KB
    __shared__ __align__(16) __bf16 Ps[4][16 * 64];    // 8 KB (XOR-swizzled)

    // decode: bid = (((31-qt)*2 + qh)*2 + b)*8 + kvh
    const int bid = blockIdx.x;                 // 0..1023
    const int kvh = bid & 7;
    int tdec = bid >> 3;
    const int b = tdec & 1; tdec >>= 1;
    const int qh = tdec & 1;
    const int qt = 31 - (tdec >> 1);
    const int h = (kvh < 4) ? (kvh * 2 + qh) : (8 + (kvh - 4) * 2 + qh);
    const int q0 = qt * 64;
    const int tid = threadIdx.x, lane = tid & 63, w = tid >> 6;
    const int lhi = lane >> 4, llo = lane & 15;
    const int gsrc = (lane & 7) ^ ((lane >> 3) & 7);
    const int win = (h < 8) ? -1 : winp[0];
    const int winv = (win < 0) ? (1 << 30) : win;

    const __bf16* kbase = qkv + (size_t)(b * 2048) * 2048 + 1024 + kvh * 64;
    const __bf16* vtbase = vT + ((size_t)((b * 8 + kvh) * 64)) * 2048;

    int kts = 0;
    if (win >= 0) { int s = q0 - win; if (s > 0) kts = s >> 6; }

    // Q fragments in registers: lane q-row = q0 + w*16 + llo
    const __bf16* qrow = qkv + (size_t)(b * 2048 + q0 + w * 16 + llo) * 2048
                         + h * 64 + lhi * 8;
    bf16x8 qf[2];
    qf[0] = *(const bf16x8*)(qrow);
    qf[1] = *(const bf16x8*)(qrow + 32);

    auto STAGE = [&](int ktx) {
        #pragma unroll
        for (int rr = 0; rr < 2; ++rr) {
            int c = rr * 4 + w;
            int r = c * 8 + (lane >> 3);
            gload16(kbase + (size_t)(ktx * 64 + r) * 2048 + gsrc * 8,
                    (char*)Ks + c * 1024);
            gload16(vtbase + (size_t)r * 2048 + ktx * 64 + gsrc * 8,
                    (char*)VTs + c * 1024);
        }
    };

    f32x4 oaccT[4] = {};
    float lrow = 0.f;                           // per-lane partial sum

    const int pswz = (llo & 7) << 4;            // per-row XOR swizzle

    for (int kt = kts; kt <= qt; ++kt) {
        STAGE(kt);
        __syncthreads();                         // vmcnt drained; tile visible

        // ---- S^T = K · Q^T : D[key][q], q = llo ----
        f32x4 sacc[4] = {};
        __builtin_amdgcn_s_setprio(1);
        #pragma unroll
        for (int ks = 0; ks < 2; ++ks) {
            #pragma unroll
            for (int kj = 0; kj < 4; ++kj) {
                int rb = kj * 16 + llo;
                bf16x8 bk = *(const bf16x8*)((const char*)&Ks[0]
                    + rb * 128 + (((ks * 4 + lhi) ^ (rb & 7)) << 4));
                sacc[kj] = MFMA16(bk, qf[ks], sacc[kj]);
            }
        }
        __builtin_amdgcn_s_setprio(0);

        const bool needMask = (kt == qt) || (win >= 0 && kt * 64 < q0 + 63 - winv);

        float sv[16];
        #pragma unroll
        for (int kj = 0; kj < 4; ++kj)
            #pragma unroll
            for (int r = 0; r < 4; ++r)
                sv[kj * 4 + r] = sacc[kj][r];
        if (needMask) {
            int qrowi = q0 + w * 16 + llo;
            #pragma unroll
            for (int kj = 0; kj < 4; ++kj)
                #pragma unroll
                for (int r = 0; r < 4; ++r) {
                    int key = kt * 64 + kj * 16 + lhi * 4 + r;
                    bool ok = (key <= qrowi) && (qrowi - key <= winv);
                    if (!ok) sv[kj * 4 + r] = -__builtin_inff();
                }
        }

        // no-bias exp2 softmax: p = 2^s (scale-invariant; |s|<=~11.8 unmasked)
        float p[16];
        #pragma unroll
        for (int t = 0; t < 16; ++t)
            p[t] = __builtin_amdgcn_exp2f(sv[t]);

        // P -> per-wave swizzled LDS (row=llo, byte=key*2 ^ pswz)
        #pragma unroll
        for (int kj = 0; kj < 4; ++kj) {
            bf16x4 pk = { (__bf16)p[kj * 4 + 0], (__bf16)p[kj * 4 + 1],
                          (__bf16)p[kj * 4 + 2], (__bf16)p[kj * 4 + 3] };
            *(bf16x4*)((char*)&Ps[w][0]
                + ((llo * 128 + kj * 32 + lhi * 8) ^ pswz)) = pk;
        }

        // tree-sum of p (depth 4)
        #pragma unroll
        for (int st = 8; st >= 1; st >>= 1)
            #pragma unroll
            for (int t = 0; t < st; ++t) p[t] += p[t + st];
        lrow += p[0];

        // ---- O^T += V^T · P^T : D[d][q], q = llo ----
        __builtin_amdgcn_s_setprio(1);
        #pragma unroll
        for (int ks = 0; ks < 2; ++ks) {
            bf16x8 ap = *(const bf16x8*)((const char*)&Ps[w][0]
                + ((llo * 128 + ks * 64 + lhi * 16) ^ pswz));
            #pragma unroll
            for (int dj = 0; dj < 4; ++dj) {
                int rv = dj * 16 + llo;
                bf16x8 bv = *(const bf16x8*)((const char*)&VTs[0]
                    + rv * 128 + (((ks * 4 + lhi) ^ (rv & 7)) << 4));
                oaccT[dj] = MFMA16(bv, ap, oaccT[dj]);
            }
        }
        __builtin_amdgcn_s_setprio(0);

        __syncthreads();                         // reads done before next STAGE
    }

    // final cross-lane lrow reduction (once)
    lrow += __shfl_xor(lrow, 16, 64);
    lrow += __shfl_xor(lrow, 32, 64);

    float inv = 1.0f / lrow;
    int row = b * 2048 + q0 + w * 16 + llo;
    #pragma unroll
    for (int dj = 0; dj < 4; ++dj) {
        bf16x4 o = { (__bf16)(oaccT[dj][0] * inv), (__bf16)(oaccT[dj][1] * inv),
                     (__bf16)(oaccT[dj][2] * inv), (__bf16)(oaccT[dj][3] * inv) };
        *(bf16x4*)(&y[(size_t)row * 1024 + h * 64 + dj * 16 + lhi * 4]) = o;
    }
}

// ---------------------------------------------------------------------------
extern "C" void kernel_launch(void* const* d_in, const int* in_sizes, int n_in,
                              void* d_out, int out_size, void* d_ws, size_t ws_size,
                              hipStream_t stream) {
    const float* x     = (const float*)d_in[0];
    const float* ve    = (const float*)d_in[1];
    const float* cosb  = (const float*)d_in[2];
    const float* sinb  = (const float*)d_in[3];
    const float* Wq    = (const float*)d_in[4];
    const float* Wk    = (const float*)d_in[5];
    const float* Wv    = (const float*)d_in[6];
    const float* Wproj = (const float*)d_in[7];
    const float* Wg    = (const float*)d_in[8];
    const int*   winp  = (const int*)d_in[9];

    char* ws = (char*)d_ws;
    __bf16* qkv    = (__bf16*)(ws);                       // 16 MB  [4096][2048]
    __bf16* vT     = (__bf16*)(ws + (16u << 20));         //  4 MB  [2*8*64][2048]
    __bf16* ybuf   = (__bf16*)(ws + (20u << 20));         //  8 MB  [4096][1024]
    __bf16* wqkvt  = (__bf16*)(ws + (36u << 20));         //  4 MB  [2048][1024]
    __bf16* wprojt = (__bf16*)(ws + (40u << 20));         //  2 MB  [1024][1024]

    prep3_kernel<<<1024, 256, 0, stream>>>(Wq, Wk, Wv, Wproj, wqkvt, wprojt);
    gemm_qkv<<<dim3(16, 32), 256, 0, stream>>>(x, wqkvt, qkv, 4096, 2048, 1024);
    post2_kernel<<<3584, 256, 0, stream>>>(qkv, x, ve, Wg, cosb, sinb, vT);
    attn_mfma<<<1024, 256, 0, stream>>>(qkv, vT, ybuf, winp);
    gemm64_bf16<float><<<dim3(8, 64), 256, 0, stream>>>(ybuf, wprojt, (float*)d_out, 4096, 1024, 1024);
}

// Round 19
// 100.213 us; speedup vs baseline: 1.0222x; 1.0222x over previous
//
#include <hip/hip_runtime.h>
#include <hip/hip_bf16.h>
#include <math.h>

typedef __bf16 bf16x8 __attribute__((ext_vector_type(8)));
typedef __bf16 bf16x4 __attribute__((ext_vector_type(4)));
typedef float  f32x4  __attribute__((ext_vector_type(4)));

#define MFMA16(a, b, c) __builtin_amdgcn_mfma_f32_16x16x32_bf16((a), (b), (c), 0, 0, 0)

__device__ __forceinline__ void gload16(const void* g, void* lds) {
    __builtin_amdgcn_global_load_lds(
        (const __attribute__((address_space(1))) uint32_t*)g,
        (__attribute__((address_space(3))) uint32_t*)lds, 16, 0, 0);
}

// ---------------------------------------------------------------------------
// prep2: blocks 0..4095 cast x -> bf16 ; blocks 4096..5119 transpose-cast
// weights (idx = bx-4096: n0=(idx&15)*64, k0=((idx>>4)&15)*64, z=idx>>8).
__global__ __launch_bounds__(256)
void prep2_kernel(const float* __restrict__ x, __bf16* __restrict__ xb,
                  const float* __restrict__ Wq, const float* __restrict__ Wk,
                  const float* __restrict__ Wv, const float* __restrict__ Wproj,
                  __bf16* __restrict__ wqkvt, __bf16* __restrict__ wprojt) {
    const int bx = blockIdx.x;
    const int tid = threadIdx.x;
    if (bx < 4096) {
        int i = bx * 256 + tid;
        float4 v = reinterpret_cast<const float4*>(x)[i];
        bf16x4 o = { (__bf16)v.x, (__bf16)v.y, (__bf16)v.z, (__bf16)v.w };
        *reinterpret_cast<bf16x4*>(xb + (size_t)i * 4) = o;
        return;
    }
    __shared__ __bf16 Ts[64 * 72];
    const int idx = bx - 4096;
    const int z = idx >> 8;
    const float* W = (z == 0) ? Wq : (z == 1) ? Wk : (z == 2) ? Wv : Wproj;
    __bf16* dst = (z == 3) ? wprojt : wqkvt;
    const int N = (z == 1 || z == 2) ? 512 : 1024;
    const int nt_off = (z == 1) ? 1024 : (z == 2) ? 1536 : 0;
    const int n0 = (idx & 15) * 64, k0 = ((idx >> 4) & 15) * 64;
    if (n0 >= N) return;
    {
        int r = tid >> 2;              // k-row 0..63
        int c0 = (tid & 3) * 16;       // n-col start
        const float4* s4 = reinterpret_cast<const float4*>(
            W + (size_t)(k0 + r) * N + n0 + c0);
        float val[16];
        #pragma unroll
        for (int q = 0; q < 4; ++q) {
            float4 v = s4[q];
            val[q * 4 + 0] = v.x; val[q * 4 + 1] = v.y;
            val[q * 4 + 2] = v.z; val[q * 4 + 3] = v.w;
        }
        #pragma unroll
        for (int j = 0; j < 16; ++j) Ts[(c0 + j) * 72 + r] = (__bf16)val[j];
    }
    __syncthreads();
    {
        int n = tid >> 2, kg = (tid & 3) * 16;
        __bf16* out = dst + (size_t)(nt_off + n0 + n) * 1024 + k0 + kg;
        bf16x8 t0 = *reinterpret_cast<const bf16x8*>(&Ts[n * 72 + kg]);
        bf16x8 t1 = *reinterpret_cast<const bf16x8*>(&Ts[n * 72 + kg + 8]);
        *reinterpret_cast<bf16x8*>(out) = t0;
        *reinterpret_cast<bf16x8*>(out + 8) = t1;
    }
}

// ---------------------------------------------------------------------------
// bf16 MFMA GEMM: C(MxN) = A(MxK) @ Bt(NxK)^T ; 128x128 tile, BK=64, 4 waves,
// XCD-aware block swizzle. (qkv: grid (16,32) = 512 blocks = 2/CU)
template <typename OutT>
__global__ __launch_bounds__(256)
void gemm_bf16(const __bf16* __restrict__ A, const __bf16* __restrict__ Bt,
               OutT* __restrict__ C, int M, int N, int K) {
    __shared__ __align__(16) __bf16 As[128 * 64];
    __shared__ __align__(16) __bf16 Bs[128 * 64];
    const int tid = threadIdx.x;
    const int lane = tid & 63, w = tid >> 6;
    const int wr = w >> 1, wc = w & 1;
    const int nwg = gridDim.x * gridDim.y;
    const int id = blockIdx.y * gridDim.x + blockIdx.x;
    const int nid = (id & 7) * (nwg >> 3) + (id >> 3);
    const int bxs = nid % gridDim.x, bys = nid / gridDim.x;
    const int bm = bys * 128, bn = bxs * 128;
    const int lhi = lane >> 4, llo = lane & 15;
    const int gsrc = (lane & 7) ^ ((lane >> 3) & 7);   // pre-swizzled source group

    f32x4 acc[4][4] = {};

    for (int k0 = 0; k0 < K; k0 += 64) {
        __syncthreads();
        const __bf16* Ab = A + (size_t)bm * K + k0;
        const __bf16* Bb = Bt + (size_t)bn * K + k0;
        #pragma unroll
        for (int rr = 0; rr < 4; ++rr) {
            int c = rr * 4 + w;
            int r = c * 8 + (lane >> 3);
            gload16(Ab + (size_t)r * K + gsrc * 8, (char*)As + c * 1024);
            gload16(Bb + (size_t)r * K + gsrc * 8, (char*)Bs + c * 1024);
        }
        __syncthreads();

        #pragma unroll
        for (int ks = 0; ks < 2; ++ks) {
            bf16x8 af[4], bfr[4];
            int g = ks * 4 + lhi;
            #pragma unroll
            for (int i = 0; i < 4; ++i) {
                int ra = wr * 64 + i * 16 + llo;
                af[i] = *reinterpret_cast<const bf16x8*>(
                    (const char*)As + ra * 128 + ((g ^ (ra & 7)) << 4));
                int rb = wc * 64 + i * 16 + llo;
                bfr[i] = *reinterpret_cast<const bf16x8*>(
                    (const char*)Bs + rb * 128 + ((g ^ (rb & 7)) << 4));
            }
            #pragma unroll
            for (int i = 0; i < 4; ++i)
                #pragma unroll
                for (int j = 0; j < 4; ++j)
                    acc[i][j] = MFMA16(af[i], bfr[j], acc[i][j]);
        }
    }

    #pragma unroll
    for (int i = 0; i < 4; ++i) {
        #pragma unroll
        for (int j = 0; j < 4; ++j) {
            int col = bn + wc * 64 + j * 16 + llo;
            #pragma unroll
            for (int r = 0; r < 4; ++r) {
                int row = bm + wr * 64 + i * 16 + lhi * 4 + r;
                C[(size_t)row * N + col] = (OutT)acc[i][j][r];
            }
        }
    }
}

// ---------------------------------------------------------------------------
// gemm64: 64(M) x 128(N) tile, BK=64, 4 waves each 64x32. For shapes where
// the 128x128 grid gives only 1 block/CU (proj). Grid (8,64) = 512 = 2/CU.
template <typename OutT>
__global__ __launch_bounds__(256)
void gemm64_bf16(const __bf16* __restrict__ A, const __bf16* __restrict__ Bt,
                 OutT* __restrict__ C, int M, int N, int K) {
    __shared__ __align__(16) __bf16 As[64 * 64];     //  8 KB
    __shared__ __align__(16) __bf16 Bs[128 * 64];    // 16 KB
    const int tid = threadIdx.x;
    const int lane = tid & 63, w = tid >> 6;
    const int nwg = gridDim.x * gridDim.y;
    const int id = blockIdx.y * gridDim.x + blockIdx.x;
    const int nid = (id & 7) * (nwg >> 3) + (id >> 3);
    const int bxs = nid % gridDim.x, bys = nid / gridDim.x;
    const int bm = bys * 64, bn = bxs * 128;
    const int lhi = lane >> 4, llo = lane & 15;
    const int gsrc = (lane & 7) ^ ((lane >> 3) & 7);

    f32x4 acc[4][2] = {};

    for (int k0 = 0; k0 < K; k0 += 64) {
        __syncthreads();
        const __bf16* Ab = A + (size_t)bm * K + k0;
        const __bf16* Bb = Bt + (size_t)bn * K + k0;
        #pragma unroll
        for (int rr = 0; rr < 2; ++rr) {
            int c = rr * 4 + w;            // 0..7
            int r = c * 8 + (lane >> 3);   // 0..63
            gload16(Ab + (size_t)r * K + gsrc * 8, (char*)As + c * 1024);
        }
        #pragma unroll
        for (int rr = 0; rr < 4; ++rr) {
            int c = rr * 4 + w;            // 0..15
            int r = c * 8 + (lane >> 3);   // 0..127
            gload16(Bb + (size_t)r * K + gsrc * 8, (char*)Bs + c * 1024);
        }
        __syncthreads();

        #pragma unroll
        for (int ks = 0; ks < 2; ++ks) {
            int g = ks * 4 + lhi;
            bf16x8 af[4], bfr[2];
            #pragma unroll
            for (int i = 0; i < 4; ++i) {
                int ra = i * 16 + llo;
                af[i] = *reinterpret_cast<const bf16x8*>(
                    (const char*)As + ra * 128 + ((g ^ (ra & 7)) << 4));
            }
            #pragma unroll
            for (int j = 0; j < 2; ++j) {
                int rb = w * 32 + j * 16 + llo;
                bfr[j] = *reinterpret_cast<const bf16x8*>(
                    (const char*)Bs + rb * 128 + ((g ^ (rb & 7)) << 4));
            }
            #pragma unroll
            for (int i = 0; i < 4; ++i)
                #pragma unroll
                for (int j = 0; j < 2; ++j)
                    acc[i][j] = MFMA16(af[i], bfr[j], acc[i][j]);
        }
    }

    #pragma unroll
    for (int i = 0; i < 4; ++i) {
        #pragma unroll
        for (int j = 0; j < 2; ++j) {
            int col = bn + w * 32 + j * 16 + llo;
            #pragma unroll
            for (int r = 0; r < 4; ++r) {
                int row = bm + i * 16 + lhi * 4 + r;
                C[(size_t)row * N + col] = (OutT)acc[i][j][r];
            }
        }
    }
}

// ---------------------------------------------------------------------------
// post2: vectorized RoPE+RMS (blocks 0..3071, 8 elems/lane) ;
// v-gate + transpose (blocks 3072..3583) with inline gate.
// Q heads scaled by 0.125*log2(e) (exp2-domain softmax).
__global__ __launch_bounds__(256)
void post2_kernel(__bf16* __restrict__ qkv, const float* __restrict__ x,
                  const float* __restrict__ ve, const float* __restrict__ Wg,
                  const float* __restrict__ cosb, const float* __restrict__ sinb,
                  __bf16* __restrict__ vT) {
    const int id = blockIdx.x;
    const int tid = threadIdx.x;
    if (id < 3072) {
        // RoPE+RMS: u = id>>7 (head unit), 32 rows/block, 8 lanes/row
        const int u = id >> 7;                      // 0..23
        const int row = (id & 127) * 32 + (tid >> 3);
        const int j = tid & 7;                      // 8 elems each
        const int t = row & 2047;
        const int off = (u < 16) ? u * 64 : 1024 + (u - 16) * 64;
        __bf16* p = qkv + (size_t)row * 2048 + off + j * 8;
        bf16x8 v8 = *(const bf16x8*)p;
        float v[8], pr[8];
        #pragma unroll
        for (int e = 0; e < 8; ++e) v[e] = (float)v8[e];
        #pragma unroll
        for (int e = 0; e < 8; ++e) pr[e] = __shfl_xor(v[e], 4, 64);  // d^32
        const float* cp = cosb + t * 32 + (j & 3) * 8;
        const float* sp = sinb + t * 32 + (j & 3) * 8;
        float4 c0 = *(const float4*)cp, c1 = *(const float4*)(cp + 4);
        float4 s0 = *(const float4*)sp, s1 = *(const float4*)(sp + 4);
        float cs[8] = {c0.x, c0.y, c0.z, c0.w, c1.x, c1.y, c1.z, c1.w};
        float sn[8] = {s0.x, s0.y, s0.z, s0.w, s1.x, s1.y, s1.z, s1.w};
        float r[8];
        if (j < 4) {
            #pragma unroll
            for (int e = 0; e < 8; ++e) r[e] = v[e] * cs[e] + pr[e] * sn[e];
        } else {
            #pragma unroll
            for (int e = 0; e < 8; ++e) r[e] = v[e] * cs[e] - pr[e] * sn[e];
        }
        float s = 0.f;
        #pragma unroll
        for (int e = 0; e < 8; ++e) s = fmaf(r[e], r[e], s);
        s += __shfl_xor(s, 1, 64);
        s += __shfl_xor(s, 2, 64);
        s += __shfl_xor(s, 4, 64);
        float scale = rsqrtf(s * (1.0f / 64.0f) + 1.1920929e-07f);
        if (u < 16) scale *= 0.18033688011116012f;  // 0.125 * log2(e)
        bf16x8 o;
        #pragma unroll
        for (int e = 0; e < 8; ++e) o[e] = (__bf16)(r[e] * scale);
        *(bf16x8*)p = o;
    } else {
        __shared__ __bf16 Ts[64 * 72];
        const int rem = id - 3072;
        const int ch = rem & 63;    // 64-row chunk
        const int h = rem >> 6;     // 0..7
        {
            int r = tid >> 2, c0 = (tid & 3) * 16;
            int grow = ch * 64 + r;
            // inline gate: 4 lanes/row each sum 8 terms, combine via shfl
            float gz = 0.f;
            {
                const float* xr = x + (size_t)grow * 1024 + (tid & 3) * 8;
                #pragma unroll
                for (int i = 0; i < 8; ++i)
                    gz = fmaf(xr[i], Wg[((tid & 3) * 8 + i) * 8 + h], gz);
                gz += __shfl_xor(gz, 1, 64);
                gz += __shfl_xor(gz, 2, 64);
            }
            float g = 2.0f / (1.0f + expf(-gz));
            const __bf16* vp = qkv + (size_t)grow * 2048 + 1536 + h * 64 + c0;
            const float* vep = ve + (size_t)grow * 512 + h * 64 + c0;
            bf16x8 v0 = *reinterpret_cast<const bf16x8*>(vp);
            bf16x8 v1 = *reinterpret_cast<const bf16x8*>(vp + 8);
            #pragma unroll
            for (int j = 0; j < 8; ++j) {
                Ts[(c0 + j) * 72 + r]     = (__bf16)((float)v0[j] + g * vep[j]);
                Ts[(c0 + 8 + j) * 72 + r] = (__bf16)((float)v1[j] + g * vep[8 + j]);
            }
        }
        __syncthreads();
        {
            int d = tid >> 2, t0l = (tid & 3) * 16;
            int b = ch >> 5, tloc = (ch & 31) * 64;
            __bf16* out = vT + ((size_t)((b * 8 + h) * 64 + d)) * 2048 + tloc + t0l;
            bf16x8 t0 = *reinterpret_cast<const bf16x8*>(&Ts[d * 72 + t0l]);
            bf16x8 t1 = *reinterpret_cast<const bf16x8*>(&Ts[d * 72 + t0l + 8]);
            *reinterpret_cast<bf16x8*>(out) = t0;
            *reinterpret_cast<bf16x8*>(out + 8) = t1;
        }
    }
}

// ---------------------------------------------------------------------------
// MFMA flash attention v9 (proven 41us): QBLK=64 (4 waves x 16 q-rows),
// KVBLK=64, grid 1024. Single-buffered gload_lds staging: STAGE -> barrier ->
// compute -> barrier. LDS = 24576 B. XCD-locality (kvh in low 3 bits), LPT,
// no-bias exp2 softmax (scale-invariant, |s|<=~11.8), tree-sum denominator.
__global__ __launch_bounds__(256, 6)
void attn_mfma(const __bf16* __restrict__ qkv, const __bf16* __restrict__ vT,
               __bf16* __restrict__ y, const int* __restrict__ winp) {
    __shared__ __align__(16) __bf16 Ks[64 * 64];       // 8 KB
    __shared__ __align__(16) __bf16 VTs[64 * 64];      // 8 KB
    __shared__ __align__(16) __bf16 Ps[4][16 * 64];    // 8 KB (XOR-swizzled)

    // decode: bid = (((31-qt)*2 + qh)*2 + b)*8 + kvh
    const int bid = blockIdx.x;                 // 0..1023
    const int kvh = bid & 7;
    int tdec = bid >> 3;
    const int b = tdec & 1; tdec >>= 1;
    const int qh = tdec & 1;
    const int qt = 31 - (tdec >> 1);
    const int h = (kvh < 4) ? (kvh * 2 + qh) : (8 + (kvh - 4) * 2 + qh);
    const int q0 = qt * 64;
    const int tid = threadIdx.x, lane = tid & 63, w = tid >> 6;
    const int lhi = lane >> 4, llo = lane & 15;
    const int gsrc = (lane & 7) ^ ((lane >> 3) & 7);
    const int win = (h < 8) ? -1 : winp[0];
    const int winv = (win < 0) ? (1 << 30) : win;

    const __bf16* kbase = qkv + (size_t)(b * 2048) * 2048 + 1024 + kvh * 64;
    const __bf16* vtbase = vT + ((size_t)((b * 8 + kvh) * 64)) * 2048;

    int kts = 0;
    if (win >= 0) { int s = q0 - win; if (s > 0) kts = s >> 6; }

    // Q fragments in registers: lane q-row = q0 + w*16 + llo
    const __bf16* qrow = qkv + (size_t)(b * 2048 + q0 + w * 16 + llo) * 2048
                         + h * 64 + lhi * 8;
    bf16x8 qf[2];
    qf[0] = *(const bf16x8*)(qrow);
    qf[1] = *(const bf16x8*)(qrow + 32);

    auto STAGE = [&](int ktx) {
        #pragma unroll
        for (int rr = 0; rr < 2; ++rr) {
            int c = rr * 4 + w;
            int r = c * 8 + (lane >> 3);
            gload16(kbase + (size_t)(ktx * 64 + r) * 2048 + gsrc * 8,
                    (char*)Ks + c * 1024);
            gload16(vtbase + (size_t)r * 2048 + ktx * 64 + gsrc * 8,
                    (char*)VTs + c * 1024);
        }
    };

    f32x4 oaccT[4] = {};
    float lrow = 0.f;                           // per-lane partial sum

    const int pswz = (llo & 7) << 4;            // per-row XOR swizzle

    for (int kt = kts; kt <= qt; ++kt) {
        STAGE(kt);
        __syncthreads();                         // vmcnt drained; tile visible

        // ---- S^T = K · Q^T : D[key][q], q = llo ----
        f32x4 sacc[4] = {};
        __builtin_amdgcn_s_setprio(1);
        #pragma unroll
        for (int ks = 0; ks < 2; ++ks) {
            #pragma unroll
            for (int kj = 0; kj < 4; ++kj) {
                int rb = kj * 16 + llo;
                bf16x8 bk = *(const bf16x8*)((const char*)&Ks[0]
                    + rb * 128 + (((ks * 4 + lhi) ^ (rb & 7)) << 4));
                sacc[kj] = MFMA16(bk, qf[ks], sacc[kj]);
            }
        }
        __builtin_amdgcn_s_setprio(0);

        const bool needMask = (kt == qt) || (win >= 0 && kt * 64 < q0 + 63 - winv);

        float sv[16];
        #pragma unroll
        for (int kj = 0; kj < 4; ++kj)
            #pragma unroll
            for (int r = 0; r < 4; ++r)
                sv[kj * 4 + r] = sacc[kj][r];
        if (needMask) {
            int qrowi = q0 + w * 16 + llo;
            #pragma unroll
            for (int kj = 0; kj < 4; ++kj)
                #pragma unroll
                for (int r = 0; r < 4; ++r) {
                    int key = kt * 64 + kj * 16 + lhi * 4 + r;
                    bool ok = (key <= qrowi) && (qrowi - key <= winv);
                    if (!ok) sv[kj * 4 + r] = -__builtin_inff();
                }
        }

        // no-bias exp2 softmax: p = 2^s (scale-invariant; |s|<=~11.8 unmasked)
        float p[16];
        #pragma unroll
        for (int t = 0; t < 16; ++t)
            p[t] = __builtin_amdgcn_exp2f(sv[t]);

        // P -> per-wave swizzled LDS (row=llo, byte=key*2 ^ pswz)
        #pragma unroll
        for (int kj = 0; kj < 4; ++kj) {
            bf16x4 pk = { (__bf16)p[kj * 4 + 0], (__bf16)p[kj * 4 + 1],
                          (__bf16)p[kj * 4 + 2], (__bf16)p[kj * 4 + 3] };
            *(bf16x4*)((char*)&Ps[w][0]
                + ((llo * 128 + kj * 32 + lhi * 8) ^ pswz)) = pk;
        }

        // tree-sum of p (depth 4)
        #pragma unroll
        for (int st = 8; st >= 1; st >>= 1)
            #pragma unroll
            for (int t = 0; t < st; ++t) p[t] += p[t + st];
        lrow += p[0];

        // ---- O^T += V^T · P^T : D[d][q], q = llo ----
        __builtin_amdgcn_s_setprio(1);
        #pragma unroll
        for (int ks = 0; ks < 2; ++ks) {
            bf16x8 ap = *(const bf16x8*)((const char*)&Ps[w][0]
                + ((llo * 128 + ks * 64 + lhi * 16) ^ pswz));
            #pragma unroll
            for (int dj = 0; dj < 4; ++dj) {
                int rv = dj * 16 + llo;
                bf16x8 bv = *(const bf16x8*)((const char*)&VTs[0]
                    + rv * 128 + (((ks * 4 + lhi) ^ (rv & 7)) << 4));
                oaccT[dj] = MFMA16(bv, ap, oaccT[dj]);
            }
        }
        __builtin_amdgcn_s_setprio(0);

        __syncthreads();                         // reads done before next STAGE
    }

    // final cross-lane lrow reduction (once)
    lrow += __shfl_xor(lrow, 16, 64);
    lrow += __shfl_xor(lrow, 32, 64);

    float inv = 1.0f / lrow;
    int row = b * 2048 + q0 + w * 16 + llo;
    #pragma unroll
    for (int dj = 0; dj < 4; ++dj) {
        bf16x4 o = { (__bf16)(oaccT[dj][0] * inv), (__bf16)(oaccT[dj][1] * inv),
                     (__bf16)(oaccT[dj][2] * inv), (__bf16)(oaccT[dj][3] * inv) };
        *(bf16x4*)(&y[(size_t)row * 1024 + h * 64 + dj * 16 + lhi * 4]) = o;
    }
}

// ---------------------------------------------------------------------------
extern "C" void kernel_launch(void* const* d_in, const int* in_sizes, int n_in,
                              void* d_out, int out_size, void* d_ws, size_t ws_size,
                              hipStream_t stream) {
    const float* x     = (const float*)d_in[0];
    const float* ve    = (const float*)d_in[1];
    const float* cosb  = (const float*)d_in[2];
    const float* sinb  = (const float*)d_in[3];
    const float* Wq    = (const float*)d_in[4];
    const float* Wk    = (const float*)d_in[5];
    const float* Wv    = (const float*)d_in[6];
    const float* Wproj = (const float*)d_in[7];
    const float* Wg    = (const float*)d_in[8];
    const int*   winp  = (const int*)d_in[9];

    char* ws = (char*)d_ws;
    __bf16* qkv    = (__bf16*)(ws);                       // 16 MB  [4096][2048]
    __bf16* vT     = (__bf16*)(ws + (16u << 20));         //  4 MB  [2*8*64][2048]
    __bf16* ybuf   = (__bf16*)(ws + (20u << 20));         //  8 MB  [4096][1024]
    __bf16* xb     = (__bf16*)(ws + (28u << 20));         //  8 MB  [4096][1024]
    __bf16* wqkvt  = (__bf16*)(ws + (36u << 20));         //  4 MB  [2048][1024]
    __bf16* wprojt = (__bf16*)(ws + (40u << 20));         //  2 MB  [1024][1024]

    prep2_kernel<<<5120, 256, 0, stream>>>(x, xb, Wq, Wk, Wv, Wproj, wqkvt, wprojt);
    gemm_bf16<__bf16><<<dim3(16, 32), 256, 0, stream>>>(xb, wqkvt, qkv, 4096, 2048, 1024);
    post2_kernel<<<3584, 256, 0, stream>>>(qkv, x, ve, Wg, cosb, sinb, vT);
    attn_mfma<<<1024, 256, 0, stream>>>(qkv, vT, ybuf, winp);
    gemm64_bf16<float><<<dim3(8, 64), 256, 0, stream>>>(ybuf, wprojt, (float*)d_out, 4096, 1024, 1024);
}